// Round 1
// baseline (695.852 us; speedup 1.0000x reference)
//
#include <hip/hip_runtime.h>

#define NUM_NODES    2000000
#define NUM_PHYSICAL 2000000
#define NBX 1024
#define NBY 1024
#define SQRT2 1.4142135623730951f

// bsx = bsy = 1.0, origin = 0. Final scale 1/(bsx*bsy*0.1) = 10.0 folded into density.

__global__ __launch_bounds__(256) void pin_util_scatter(
    const float* __restrict__ pos,
    const float* __restrict__ nsx_arr,
    const float* __restrict__ nsy_arr,
    const float* __restrict__ pw_arr,
    float* __restrict__ out)
{
    int i = blockIdx.x * blockDim.x + threadIdx.x;
    if (i >= NUM_PHYSICAL) return;

    float nsx = nsx_arr[i];
    float nsy = nsy_arr[i];
    float x   = pos[i];
    float y   = pos[NUM_NODES + i];
    float pw  = pw_arr[i];

    float hx = 0.5f * fmaxf(nsx, SQRT2);
    float hy = 0.5f * fmaxf(nsy, SQRT2);
    float cx = x + 0.5f * nsx;
    float cy = y + 0.5f * nsy;
    float xmin = cx - hx, xmax = cx + hx;
    float ymin = cy - hy, ymax = cy + hy;

    int blx = max((int)floorf(xmin), 0);
    int bhx = min((int)floorf(xmax) + 1, NBX);
    int bly = max((int)floorf(ymin), 0);
    int bhy = min((int)floorf(ymax) + 1, NBY);

    // density * 10 (folded output scale)
    float dens = 10.0f * pw / (4.0f * hx * hy);

    // Per-axis overlaps for K=4 consecutive bins starting at bl.
    float ox[4], oy[4];
    int   bx[4], by[4];
#pragma unroll
    for (int k = 0; k < 4; ++k) {
        int b = blx + k;
        float ov = fminf((float)(b + 1), xmax) - fmaxf((float)b, xmin);
        ox[k] = (b < bhx) ? ov : 0.0f;
        bx[k] = min(b, NBX - 1);
    }
#pragma unroll
    for (int k = 0; k < 4; ++k) {
        int b = bly + k;
        float ov = fminf((float)(b + 1), ymax) - fmaxf((float)b, ymin);
        oy[k] = (b < bhy) ? ov : 0.0f;
        by[k] = min(b, NBY - 1);
    }

#pragma unroll
    for (int kx = 0; kx < 4; ++kx) {
        if (ox[kx] == 0.0f) continue;
        float dx = dens * ox[kx];
        int rowbase = bx[kx] * NBY;
#pragma unroll
        for (int ky = 0; ky < 4; ++ky) {
            if (oy[ky] == 0.0f) continue;
            atomicAdd(&out[rowbase + by[ky]], dx * oy[ky]);
        }
    }
}

extern "C" void kernel_launch(void* const* d_in, const int* in_sizes, int n_in,
                              void* d_out, int out_size, void* d_ws, size_t ws_size,
                              hipStream_t stream)
{
    const float* pos = (const float*)d_in[0];
    const float* nsx = (const float*)d_in[1];
    const float* nsy = (const float*)d_in[2];
    const float* pw  = (const float*)d_in[3];
    float* out = (float*)d_out;

    // d_out is poisoned 0xAA before every call — zero it (capturable memset node).
    hipMemsetAsync(out, 0, (size_t)out_size * sizeof(float), stream);

    int threads = 256;
    int blocks = (NUM_PHYSICAL + threads - 1) / threads;
    pin_util_scatter<<<blocks, threads, 0, stream>>>(pos, nsx, nsy, pw, out);
}